// Round 6
// baseline (544.155 us; speedup 1.0000x reference)
//
#include <hip/hip_runtime.h>

#define N_ATOMS   100000
#define N_BONDS   200000
#define MSG_ROWS  200064   // padded to multiple of 128 for k_mp tiles
#define MAX_NB    6
#define AF        39
#define BFEAT     50      // 39 + 11
#define H         128
#define DEPTH     6
#define KS_I      2       // k-steps (32 each): binput GEMM (K=64 padded)
#define KS_IH     6       // fused [fbonds(64 pad) | nei(128)] GEMM (K=192)
#define KS_O      6       // output GEMM (K=192 padded)
#define FBW       64      // padded bf16 fbonds row width
#define FAW       64      // padded bf16 fatoms row width
#define BMP       128     // k_mp tile (bonds per block), 512 threads

typedef unsigned short ushort_t;
typedef unsigned int   uint_t;

typedef __attribute__((ext_vector_type(8))) short  bf16x8;
typedef __attribute__((ext_vector_type(4))) float  f32x4;

// hardware packed f32->bf16 (RNE)
__device__ inline uint_t cvt_pk(float lo, float hi) {
    uint_t r;
    asm("v_cvt_pk_bf16_f32 %0, %1, %2" : "=v"(r) : "v"(lo), "v"(hi));
    return r;
}
__device__ inline ushort_t f2bf(float f) { return (ushort_t)cvt_pk(f, f); }
__device__ inline float bflo(uint_t u) { union { uint_t i; float f; } v; v.i = u << 16; return v.f; }
__device__ inline float bfhi(uint_t u) { union { uint_t i; float f; } v; v.i = u & 0xffff0000u; return v.f; }

// unpack-accumulate 8 bf16 (no relu: messages stored POST-relu)
__device__ inline void addv(float* a, uint4 v) {
    a[0] += bflo(v.x); a[1] += bfhi(v.x);
    a[2] += bflo(v.y); a[3] += bfhi(v.y);
    a[4] += bflo(v.z); a[5] += bfhi(v.z);
    a[6] += bflo(v.w); a[7] += bfhi(v.w);
}

// ---------------------------------------------------------------------------
// Pack weights to MFMA B-fragment-major bf16: p[ks][nt][lane][j],
//   n = nt*16 + (lane&15),  k = ks*32 + (lane>>4)*8 + j
// pWi : K=64  (cols 0..49 = W_i)
// pWih: K=192 (cols 0..49 = W_i, 50..63 = 0, 64..191 = W_h)  <- fused residual
// pWo : K=192 (cols 0..127 = W_o[a_nei part], 128..166 = W_o[fatoms part])
// ---------------------------------------------------------------------------
__global__ __launch_bounds__(256) void k_pack(const float* __restrict__ W_i,
                                              const float* __restrict__ W_h,
                                              const float* __restrict__ W_o,
                                              ushort_t* __restrict__ pWi,
                                              ushort_t* __restrict__ pWih,
                                              ushort_t* __restrict__ pWo) {
    int id = blockIdx.x * 256 + threadIdx.x;   // 7168 ids
    int mat;
    ushort_t* dst;
    if (id < 1024)      { mat = 0; dst = pWi; }
    else if (id < 4096) { mat = 1; dst = pWih; id -= 1024; }
    else                { mat = 2; dst = pWo;  id -= 4096; }
    const int lane = id & 63;
    const int nt   = (id >> 6) & 7;
    const int ks   = id >> 9;
    const int n  = nt * 16 + (lane & 15);
    const int k0 = ks * 32 + (lane >> 4) * 8;
    float v[8];
#pragma unroll
    for (int j = 0; j < 8; ++j) {
        const int k = k0 + j;
        float x = 0.f;
        if (mat == 0) {
            if (k < BFEAT) x = W_i[n * BFEAT + k];
        } else if (mat == 1) {
            if (k < BFEAT)     x = W_i[n * BFEAT + k];
            else if (k >= FBW) x = W_h[n * H + (k - FBW)];
        } else {
            if (k < H)           x = W_o[(size_t)n * (AF + H) + AF + k];
            else if (k < H + AF) x = W_o[(size_t)n * (AF + H) + (k - H)];
        }
        v[j] = x;
    }
    uint4 u;
    u.x = cvt_pk(v[0], v[1]); u.y = cvt_pk(v[2], v[3]);
    u.z = cvt_pk(v[4], v[5]); u.w = cvt_pk(v[6], v[7]);
    ((uint4*)dst)[id] = u;
}

// ---------------------------------------------------------------------------
// Pad fatoms to bf16[N_ATOMS][64] (MFMA-fragment-readable) for k_out.
// ---------------------------------------------------------------------------
__global__ __launch_bounds__(256) void k_fab(const float* __restrict__ fatoms,
                                             ushort_t* __restrict__ fab) {
    const int t = threadIdx.x;
    const int a0 = blockIdx.x * 64;
    const int row = t >> 2;
    const int c0 = (t & 3) * 16;
    const int a = a0 + row;
    if (a >= N_ATOMS) return;
    float v[16];
#pragma unroll
    for (int j = 0; j < 16; ++j) {
        const int c = c0 + j;
        v[j] = (c < AF) ? fatoms[(size_t)a * AF + c] : 0.f;
    }
    uint4 u0, u1;
    u0.x = cvt_pk(v[0],  v[1]);  u0.y = cvt_pk(v[2],  v[3]);
    u0.z = cvt_pk(v[4],  v[5]);  u0.w = cvt_pk(v[6],  v[7]);
    u1.x = cvt_pk(v[8],  v[9]);  u1.y = cvt_pk(v[10], v[11]);
    u1.z = cvt_pk(v[12], v[13]); u1.w = cvt_pk(v[14], v[15]);
    *(uint4*)(fab + (size_t)a * FAW + c0)     = u0;
    *(uint4*)(fab + (size_t)a * FAW + c0 + 8) = u1;
}

// ---------------------------------------------------------------------------
// msg0 = relu(fbonds @ W_i^T) in bf16 (POST-relu), and dump padded bf16
// fbonds rows (width 64) for the fused k_mp steps.
// ---------------------------------------------------------------------------
__global__ __launch_bounds__(256) void k_binput(const float* __restrict__ fbonds,
                                                const ushort_t* __restrict__ pWi,
                                                ushort_t* __restrict__ fbb,
                                                ushort_t* __restrict__ msg0) {
    __shared__ __align__(16) ushort_t sAC[64][136];
    const int t = threadIdx.x;
    const int b0 = blockIdx.x * 64;

    for (int i = t; i < 64 * 25; i += 256) {
        const int row = i / 25, j = i % 25;
        const float2 v = *(const float2*)(fbonds + (size_t)(b0 + row) * BFEAT + j * 2);
        *(uint_t*)&sAC[row][j * 2] = cvt_pk(v.x, v.y);
    }
    for (int i = t; i < 64 * 7; i += 256) {
        const int row = i / 7, c = BFEAT + (i % 7) * 2;
        *(uint_t*)&sAC[row][c] = 0u;
    }
    __syncthreads();

    // persist bf16 fbonds (64 cols incl. zero pad) -> fbb
    for (int i = t; i < 64 * 8; i += 256) {
        const int row = i >> 3, c0 = (i & 7) * 8;
        *(uint4*)(fbb + (size_t)(b0 + row) * FBW + c0) = *(const uint4*)&sAC[row][c0];
    }

    const int w    = t >> 6;
    const int lane = t & 63;
    const int col  = lane & 15;
    const int kg   = lane >> 4;
    const int m    = 16 * w + col;

    f32x4 acc[8];
#pragma unroll
    for (int nt = 0; nt < 8; ++nt) acc[nt] = (f32x4){0.f, 0.f, 0.f, 0.f};
    bf16x8 af[KS_I];
#pragma unroll
    for (int ks = 0; ks < KS_I; ++ks)
        af[ks] = *(const bf16x8*)&sAC[m][ks * 32 + kg * 8];
#pragma unroll
    for (int ks = 0; ks < KS_I; ++ks) {
#pragma unroll
        for (int nt = 0; nt < 8; ++nt) {
            const bf16x8 b = *(const bf16x8*)(pWi + (((size_t)(ks * 8 + nt) * 64 + lane) * 8));
            acc[nt] = __builtin_amdgcn_mfma_f32_16x16x32_bf16(af[ks], b, acc[nt], 0, 0, 0);
        }
    }
    __syncthreads();   // fbb-copy reads done before C overwrite

    const int row0 = kg * 4;
#pragma unroll
    for (int nt = 0; nt < 8; ++nt)
#pragma unroll
        for (int r = 0; r < 4; ++r)
            sAC[16 * w + row0 + r][nt * 16 + col] = f2bf(fmaxf(acc[nt][r], 0.f));
    __syncthreads();

    for (int i = t; i < 64 * 16; i += 256) {
        const int row = i >> 4, c0 = (i & 15) * 8;
        *(uint4*)(msg0 + (size_t)(b0 + row) * H + c0) = *(const uint4*)&sAC[row][c0];
    }
}

// ---------------------------------------------------------------------------
// Fused MP step, 128-bond tiles / 512 threads / 8 waves:
// msg_out = relu([fbonds_bf16 | gather-sum(msg_in)] @ [W_i|W_h]^T)
// Same per-thread shape as the proven R3 kernel (2x12-deep merged gather,
// VGPR ~60) but half the blocks -> per-block fixed latency phases amortize.
// LDS: sAC[128][136] 34816 + sIdx 3072 = 37888 -> 4 blocks/CU x 8 waves.
// Last block handles 64 valid + 64 pad rows (buffers padded to MSG_ROWS).
// ---------------------------------------------------------------------------
__global__ __launch_bounds__(512) void k_mp(const ushort_t* __restrict__ msg_in,
                                            const int* __restrict__ bgraph,
                                            const ushort_t* __restrict__ pWih,
                                            const ushort_t* __restrict__ fbb,
                                            ushort_t* __restrict__ msg_out) {
    __shared__ __align__(16) ushort_t sAC[BMP][136];   // nei cols 0..127; C overwrites
    __shared__ __align__(16) int sIdx[BMP][MAX_NB];
    const int t = threadIdx.x;
    const int b0 = blockIdx.x * BMP;

    if (b0 + BMP <= N_BONDS) {          // fast path: 768 ints = 192 int4
        if (t < 192)
            ((int4*)sIdx)[t] = ((const int4*)(bgraph + (size_t)b0 * MAX_NB))[t];
    } else {                             // last block: guarded scalar staging
        for (int i = t; i < BMP * MAX_NB; i += 512) {
            const int row = b0 + i / MAX_NB;
            sIdx[i / MAX_NB][i % MAX_NB] =
                (row < N_BONDS) ? bgraph[(size_t)row * MAX_NB + (i % MAX_NB)] : 0;
        }
    }
    __syncthreads();

    {   // gather-sum: 4 rows x 6 nb per thread, two merged 12-deep passes
        const int rg = t >> 4;          // 0..31
        const int c0 = (t & 15) * 8;
#pragma unroll
        for (int p = 0; p < 4; p += 2) {
            const int iA = p * 32 + rg;
            const int iB = iA + 32;
            uint4 vA[MAX_NB], vB[MAX_NB];
#pragma unroll
            for (int j = 0; j < MAX_NB; ++j)
                vA[j] = *(const uint4*)(msg_in + (size_t)sIdx[iA][j] * H + c0);
#pragma unroll
            for (int j = 0; j < MAX_NB; ++j)
                vB[j] = *(const uint4*)(msg_in + (size_t)sIdx[iB][j] * H + c0);
            float a8[8], b8[8];
#pragma unroll
            for (int q = 0; q < 8; ++q) { a8[q] = 0.f; b8[q] = 0.f; }
#pragma unroll
            for (int j = 0; j < MAX_NB; ++j) addv(a8, vA[j]);
#pragma unroll
            for (int j = 0; j < MAX_NB; ++j) addv(b8, vB[j]);
            uint4 ua, ub;
            ua.x = cvt_pk(a8[0], a8[1]); ua.y = cvt_pk(a8[2], a8[3]);
            ua.z = cvt_pk(a8[4], a8[5]); ua.w = cvt_pk(a8[6], a8[7]);
            ub.x = cvt_pk(b8[0], b8[1]); ub.y = cvt_pk(b8[2], b8[3]);
            ub.z = cvt_pk(b8[4], b8[5]); ub.w = cvt_pk(b8[6], b8[7]);
            *(uint4*)&sAC[iA][c0] = ua;
            *(uint4*)&sAC[iB][c0] = ub;
        }
    }

    const int w    = t >> 6;            // 0..7: wave w owns M-rows 16w..16w+15
    const int lane = t & 63;
    const int col  = lane & 15;
    const int kg   = lane >> 4;
    const int m    = 16 * w + col;

    bf16x8 af[KS_IH];
    // fbonds frags direct from global (latency hides under barrier wait)
    af[0] = *(const bf16x8*)(fbb + (size_t)(b0 + m) * FBW + kg * 8);
    af[1] = *(const bf16x8*)(fbb + (size_t)(b0 + m) * FBW + 32 + kg * 8);
    __syncthreads();
#pragma unroll
    for (int ks = 2; ks < KS_IH; ++ks)
        af[ks] = *(const bf16x8*)&sAC[m][(ks - 2) * 32 + kg * 8];

    f32x4 acc[8];
#pragma unroll
    for (int nt = 0; nt < 8; ++nt) acc[nt] = (f32x4){0.f, 0.f, 0.f, 0.f};
#pragma unroll
    for (int ks = 0; ks < KS_IH; ++ks) {
#pragma unroll
        for (int nt = 0; nt < 8; ++nt) {
            const bf16x8 b = *(const bf16x8*)(pWih + (((size_t)(ks * 8 + nt) * 64 + lane) * 8));
            acc[nt] = __builtin_amdgcn_mfma_f32_16x16x32_bf16(af[ks], b, acc[nt], 0, 0, 0);
        }
    }
    // relu + bf16 C into own rows (per-wave slab; af pre-loaded, no barrier)
    const int row0 = kg * 4;
#pragma unroll
    for (int nt = 0; nt < 8; ++nt)
#pragma unroll
        for (int r = 0; r < 4; ++r)
            sAC[16 * w + row0 + r][nt * 16 + col] = f2bf(fmaxf(acc[nt][r], 0.f));
    __syncthreads();

#pragma unroll
    for (int p = 0; p < 4; ++p) {
        const int i = t + p * 512;
        const int row = i >> 4, c0 = (i & 15) * 8;
        *(uint4*)(msg_out + (size_t)(b0 + row) * H + c0) = *(const uint4*)&sAC[row][c0];
    }
}

// ---------------------------------------------------------------------------
// Fused output: out = relu(b_o + [gather(128) | fatoms_bf16(64)] @ W_o^T)
// f32 C staged through a HALF-width LDS buffer in two passes (cols 0..63,
// 64..127): keeps the coalesced float4 epilogue AND full f32 precision
// while cutting LDS 35328 -> 18944 (8 blocks/CU, all 1563 blocks resident).
// ---------------------------------------------------------------------------
__global__ __launch_bounds__(256) void k_out(const ushort_t* __restrict__ msg,
                                             const int* __restrict__ agraph,
                                             const ushort_t* __restrict__ fab,
                                             const ushort_t* __restrict__ pWo,
                                             const float* __restrict__ b_o,
                                             float* __restrict__ out) {
    __shared__ __align__(16) unsigned char smem[64 * 136 * 2];   // 17408 B union
    ushort_t (*sA)[136] = (ushort_t(*)[136])smem;                // bf16 A tile
    float    (*sCh)[68] = (float(*)[68])smem;                    // f32 C half
    __shared__ int sIdx[64][MAX_NB];
    const int t = threadIdx.x;
    const int a0 = blockIdx.x * 64;

    for (int i = t; i < 64 * MAX_NB; i += 256) {
        const int a = a0 + i / MAX_NB;
        sIdx[i / MAX_NB][i % MAX_NB] = (a < N_ATOMS) ? agraph[(size_t)a * MAX_NB + (i % MAX_NB)] : 0;
    }
    __syncthreads();

    {   // a_nei gather-sum -> cols 0..127, two merged 12-deep passes
        const int bi = t >> 4;
        const int c0 = (t & 15) * 8;
#pragma unroll
        for (int p = 0; p < 4; p += 2) {
            const int iA = p * 16 + bi;
            const int iB = iA + 16;
            uint4 vA[MAX_NB], vB[MAX_NB];
#pragma unroll
            for (int j = 0; j < MAX_NB; ++j)
                vA[j] = *(const uint4*)(msg + (size_t)sIdx[iA][j] * H + c0);
#pragma unroll
            for (int j = 0; j < MAX_NB; ++j)
                vB[j] = *(const uint4*)(msg + (size_t)sIdx[iB][j] * H + c0);
            float a8[8], b8[8];
#pragma unroll
            for (int q = 0; q < 8; ++q) { a8[q] = 0.f; b8[q] = 0.f; }
#pragma unroll
            for (int j = 0; j < MAX_NB; ++j) addv(a8, vA[j]);
#pragma unroll
            for (int j = 0; j < MAX_NB; ++j) addv(b8, vB[j]);
            uint4 ua, ub;
            ua.x = cvt_pk(a8[0], a8[1]); ua.y = cvt_pk(a8[2], a8[3]);
            ua.z = cvt_pk(a8[4], a8[5]); ua.w = cvt_pk(a8[6], a8[7]);
            ub.x = cvt_pk(b8[0], b8[1]); ub.y = cvt_pk(b8[2], b8[3]);
            ub.z = cvt_pk(b8[4], b8[5]); ub.w = cvt_pk(b8[6], b8[7]);
            *(uint4*)&sA[iA][c0] = ua;
            *(uint4*)&sA[iB][c0] = ub;
        }
    }

    const int w    = t >> 6;
    const int lane = t & 63;
    const int col  = lane & 15;
    const int kg   = lane >> 4;
    const int m    = 16 * w + col;
    const int am   = a0 + m;
    const size_t amc = (size_t)((am < N_ATOMS) ? am : 0);   // clamp (unused rows)

    bf16x8 af[KS_O];
    af[4] = *(const bf16x8*)(fab + amc * FAW + kg * 8);
    af[5] = *(const bf16x8*)(fab + amc * FAW + 32 + kg * 8);
    __syncthreads();
#pragma unroll
    for (int ks = 0; ks < 4; ++ks)
        af[ks] = *(const bf16x8*)&sA[m][ks * 32 + kg * 8];

    f32x4 acc[8];
#pragma unroll
    for (int nt = 0; nt < 8; ++nt) acc[nt] = (f32x4){0.f, 0.f, 0.f, 0.f};
#pragma unroll
    for (int ks = 0; ks < KS_O; ++ks) {
#pragma unroll
        for (int nt = 0; nt < 8; ++nt) {
            const bf16x8 b = *(const bf16x8*)(pWo + (((size_t)(ks * 8 + nt) * 64 + lane) * 8));
            acc[nt] = __builtin_amdgcn_mfma_f32_16x16x32_bf16(af[ks], b, acc[nt], 0, 0, 0);
        }
    }
    __syncthreads();   // all sA ds_reads done before C-half overwrites (union)

    const int row0 = kg * 4;
    const float4* bo4 = (const float4*)b_o;
#pragma unroll
    for (int half = 0; half < 2; ++half) {
#pragma unroll
        for (int nt = 0; nt < 4; ++nt)
#pragma unroll
            for (int r = 0; r < 4; ++r)
                sCh[16 * w + row0 + r][nt * 16 + col] = acc[half * 4 + nt][r];
        __syncthreads();
        // copy: 64 rows x 64 cols f32 = 4096 = 256 thr x 16 (4x float4)
#pragma unroll
        for (int p = 0; p < 4; ++p) {
            const int i = t + p * 256;
            const int row = i >> 4, c0 = (i & 15) * 4;
            const int a = a0 + row;
            if (a < N_ATOMS) {
                float4 cv = *(const float4*)&sCh[row][c0];
                const float4 bv = bo4[(half * 64 + c0) >> 2];
                cv.x = fmaxf(cv.x + bv.x, 0.f); cv.y = fmaxf(cv.y + bv.y, 0.f);
                cv.z = fmaxf(cv.z + bv.z, 0.f); cv.w = fmaxf(cv.w + bv.w, 0.f);
                *(float4*)(out + (size_t)a * H + half * 64 + c0) = cv;
            }
        }
        if (half == 0) __syncthreads();   // copy reads done before half-1 writes
    }
}

// ---------------------------------------------------------------------------
extern "C" void kernel_launch(void* const* d_in, const int* in_sizes, int n_in,
                              void* d_out, int out_size, void* d_ws, size_t ws_size,
                              hipStream_t stream) {
    const float* fatoms = (const float*)d_in[0];
    const float* fbonds = (const float*)d_in[1];
    const int*   agraph = (const int*)d_in[2];
    const int*   bgraph = (const int*)d_in[3];
    const float* W_i    = (const float*)d_in[4];
    const float* W_h    = (const float*)d_in[5];
    const float* W_o    = (const float*)d_in[6];
    const float* b_o    = (const float*)d_in[7];
    float* out = (float*)d_out;

    const size_t MSG_BYTES = (size_t)MSG_ROWS * H * sizeof(ushort_t);     // 51.2 MB (padded)
    const size_t FBB_BYTES = (size_t)MSG_ROWS * FBW * sizeof(ushort_t);   // 25.6 MB (padded)
    const size_t FAB_BYTES = (size_t)N_ATOMS * FAW * sizeof(ushort_t);    // 12.8 MB
    char* ws = (char*)d_ws;
    ushort_t* m0   = (ushort_t*)(ws);
    ushort_t* m1   = (ushort_t*)(ws + MSG_BYTES);
    ushort_t* fbb  = (ushort_t*)(ws + 2 * MSG_BYTES);
    ushort_t* fab  = (ushort_t*)(ws + 2 * MSG_BYTES + FBB_BYTES);
    char*     wb   = ws + 2 * MSG_BYTES + FBB_BYTES + FAB_BYTES;
    ushort_t* pWi  = (ushort_t*)(wb);              // 16 KB
    ushort_t* pWih = (ushort_t*)(wb + 16 * 1024);  // 48 KB
    ushort_t* pWo  = (ushort_t*)(wb + 64 * 1024);  // 48 KB

    k_pack<<<28, 256, 0, stream>>>(W_i, W_h, W_o, pWi, pWih, pWo);
    k_fab<<<(N_ATOMS + 63) / 64, 256, 0, stream>>>(fatoms, fab);
    k_binput<<<N_BONDS / 64, 256, 0, stream>>>(fbonds, pWi, fbb, m0);

    ushort_t* cur = m0;
    ushort_t* nxt = m1;
    const int gmp = (N_BONDS + BMP - 1) / BMP;   // 1563 (last block: 64 valid + 64 pad)
    for (int d = 0; d < DEPTH - 1; ++d) {
        k_mp<<<gmp, 512, 0, stream>>>(cur, bgraph, pWih, fbb, nxt);
        ushort_t* tmp = cur; cur = nxt; nxt = tmp;
    }

    k_out<<<(N_ATOMS + 63) / 64, 256, 0, stream>>>(cur, agraph, fab, pWo, b_o, out);
}

// Round 7
// 461.522 us; speedup vs baseline: 1.1790x; 1.1790x over previous
//
#include <hip/hip_runtime.h>

#define N_ATOMS   100000
#define N_BONDS   200000
#define MAX_NB    6
#define AF        39
#define BFEAT     50      // 39 + 11
#define H         128
#define DEPTH     6
#define KS_I      2       // k-steps (32 each): binput GEMM (K=64 padded)
#define KS_IH     6       // fused [fbonds(64 pad) | nei(128)] GEMM (K=192)
#define KS_O      6       // output GEMM (K=192 padded)
#define FBW       64      // padded fp16 fbonds row width
#define FAW       64      // padded fp16 fatoms row width

typedef unsigned short ushort_t;
typedef unsigned int   uint_t;

typedef __attribute__((ext_vector_type(8))) _Float16 f16x8;
typedef __attribute__((ext_vector_type(4))) float    f32x4;

// f32 pair -> packed fp16 (v_cvt_pkrtz_f16_f32, single op; RTZ max rel err
// 2^-10 — still 4x tighter than the bf16-RNE this replaces)
__device__ inline uint_t pkh(float lo, float hi) {
    uint_t r;
    asm("v_cvt_pkrtz_f16_f32 %0, %1, %2" : "=v"(r) : "v"(lo), "v"(hi));
    return r;
}
// scalar f32 -> fp16 (RNE via v_cvt_f16_f32)
__device__ inline ushort_t f2h(float f) {
    union { _Float16 h; ushort_t u; } v; v.h = (_Float16)f; return v.u;
}
// packed fp16 add (v_pk_add_f16): 2 lanes/op — the gather-sum workhorse
__device__ inline uint_t pkadd(uint_t a, uint_t b) {
    uint_t r;
    asm("v_pk_add_f16 %0, %1, %2" : "=v"(r) : "v"(a), "v"(b));
    return r;
}
__device__ inline void addq(uint4& a, uint4 v) {
    a.x = pkadd(a.x, v.x); a.y = pkadd(a.y, v.y);
    a.z = pkadd(a.z, v.z); a.w = pkadd(a.w, v.w);
}

// ---------------------------------------------------------------------------
// Pack weights to MFMA B-fragment-major fp16: p[ks][nt][lane][j],
//   n = nt*16 + (lane&15),  k = ks*32 + (lane>>4)*8 + j
// pWi : K=64  (cols 0..49 = W_i)
// pWih: K=192 (cols 0..49 = W_i, 50..63 = 0, 64..191 = W_h)  <- fused residual
// pWo : K=192 (cols 0..127 = W_o[a_nei part], 128..166 = W_o[fatoms part])
// ---------------------------------------------------------------------------
__global__ __launch_bounds__(256) void k_pack(const float* __restrict__ W_i,
                                              const float* __restrict__ W_h,
                                              const float* __restrict__ W_o,
                                              ushort_t* __restrict__ pWi,
                                              ushort_t* __restrict__ pWih,
                                              ushort_t* __restrict__ pWo) {
    int id = blockIdx.x * 256 + threadIdx.x;   // 7168 ids
    int mat;
    ushort_t* dst;
    if (id < 1024)      { mat = 0; dst = pWi; }
    else if (id < 4096) { mat = 1; dst = pWih; id -= 1024; }
    else                { mat = 2; dst = pWo;  id -= 4096; }
    const int lane = id & 63;
    const int nt   = (id >> 6) & 7;
    const int ks   = id >> 9;
    const int n  = nt * 16 + (lane & 15);
    const int k0 = ks * 32 + (lane >> 4) * 8;
    float v[8];
#pragma unroll
    for (int j = 0; j < 8; ++j) {
        const int k = k0 + j;
        float x = 0.f;
        if (mat == 0) {
            if (k < BFEAT) x = W_i[n * BFEAT + k];
        } else if (mat == 1) {
            if (k < BFEAT)     x = W_i[n * BFEAT + k];
            else if (k >= FBW) x = W_h[n * H + (k - FBW)];
        } else {
            if (k < H)           x = W_o[(size_t)n * (AF + H) + AF + k];
            else if (k < H + AF) x = W_o[(size_t)n * (AF + H) + (k - H)];
        }
        v[j] = x;
    }
    uint4 u;
    u.x = pkh(v[0], v[1]); u.y = pkh(v[2], v[3]);
    u.z = pkh(v[4], v[5]); u.w = pkh(v[6], v[7]);
    ((uint4*)dst)[id] = u;
}

// ---------------------------------------------------------------------------
// Pad fatoms to fp16[N_ATOMS][64] (MFMA-fragment-readable) for k_out.
// ---------------------------------------------------------------------------
__global__ __launch_bounds__(256) void k_fab(const float* __restrict__ fatoms,
                                             ushort_t* __restrict__ fab) {
    const int t = threadIdx.x;
    const int a0 = blockIdx.x * 64;
    const int row = t >> 2;
    const int c0 = (t & 3) * 16;
    const int a = a0 + row;
    if (a >= N_ATOMS) return;
    float v[16];
#pragma unroll
    for (int j = 0; j < 16; ++j) {
        const int c = c0 + j;
        v[j] = (c < AF) ? fatoms[(size_t)a * AF + c] : 0.f;
    }
    uint4 u0, u1;
    u0.x = pkh(v[0],  v[1]);  u0.y = pkh(v[2],  v[3]);
    u0.z = pkh(v[4],  v[5]);  u0.w = pkh(v[6],  v[7]);
    u1.x = pkh(v[8],  v[9]);  u1.y = pkh(v[10], v[11]);
    u1.z = pkh(v[12], v[13]); u1.w = pkh(v[14], v[15]);
    *(uint4*)(fab + (size_t)a * FAW + c0)     = u0;
    *(uint4*)(fab + (size_t)a * FAW + c0 + 8) = u1;
}

// ---------------------------------------------------------------------------
// msg0 = relu(fbonds @ W_i^T) in fp16 (POST-relu), and dump padded fp16
// fbonds rows (width 64) for the fused k_mp steps.
// ---------------------------------------------------------------------------
__global__ __launch_bounds__(256) void k_binput(const float* __restrict__ fbonds,
                                                const ushort_t* __restrict__ pWi,
                                                ushort_t* __restrict__ fbb,
                                                ushort_t* __restrict__ msg0) {
    __shared__ __align__(16) ushort_t sAC[64][136];
    const int t = threadIdx.x;
    const int b0 = blockIdx.x * 64;

    for (int i = t; i < 64 * 25; i += 256) {
        const int row = i / 25, j = i % 25;
        const float2 v = *(const float2*)(fbonds + (size_t)(b0 + row) * BFEAT + j * 2);
        *(uint_t*)&sAC[row][j * 2] = pkh(v.x, v.y);
    }
    for (int i = t; i < 64 * 7; i += 256) {
        const int row = i / 7, c = BFEAT + (i % 7) * 2;
        *(uint_t*)&sAC[row][c] = 0u;
    }
    __syncthreads();

    // persist fp16 fbonds (64 cols incl. zero pad) -> fbb
    for (int i = t; i < 64 * 8; i += 256) {
        const int row = i >> 3, c0 = (i & 7) * 8;
        *(uint4*)(fbb + (size_t)(b0 + row) * FBW + c0) = *(const uint4*)&sAC[row][c0];
    }

    const int w    = t >> 6;
    const int lane = t & 63;
    const int col  = lane & 15;
    const int kg   = lane >> 4;
    const int m    = 16 * w + col;

    f32x4 acc[8];
#pragma unroll
    for (int nt = 0; nt < 8; ++nt) acc[nt] = (f32x4){0.f, 0.f, 0.f, 0.f};
    f16x8 af[KS_I];
#pragma unroll
    for (int ks = 0; ks < KS_I; ++ks)
        af[ks] = *(const f16x8*)&sAC[m][ks * 32 + kg * 8];
#pragma unroll
    for (int ks = 0; ks < KS_I; ++ks) {
#pragma unroll
        for (int nt = 0; nt < 8; ++nt) {
            const f16x8 b = *(const f16x8*)(pWi + (((size_t)(ks * 8 + nt) * 64 + lane) * 8));
            acc[nt] = __builtin_amdgcn_mfma_f32_16x16x32_f16(af[ks], b, acc[nt], 0, 0, 0);
        }
    }
    __syncthreads();   // fbb-copy reads done before C overwrite

    const int row0 = kg * 4;
#pragma unroll
    for (int nt = 0; nt < 8; ++nt)
#pragma unroll
        for (int r = 0; r < 4; ++r)
            sAC[16 * w + row0 + r][nt * 16 + col] = f2h(fmaxf(acc[nt][r], 0.f));
    __syncthreads();

    for (int i = t; i < 64 * 16; i += 256) {
        const int row = i >> 4, c0 = (i & 15) * 8;
        *(uint4*)(msg0 + (size_t)(b0 + row) * H + c0) = *(const uint4*)&sAC[row][c0];
    }
}

// ---------------------------------------------------------------------------
// Fused MP step (R3 structure, fp16 datapath):
// msg_out = relu([fbonds_f16 | gather-sum(msg_in)] @ [W_i|W_h]^T)
// Gather-sum is native packed fp16 (v_pk_add_f16): per 12-load pass the
// ~104-op unpack/add/cvt chain of the bf16 version becomes ~40 ops and the
// accumulator IS the stored format (no repack). 64-row tiles / 256 thr /
// 2x12-deep merged passes — the proven R3 local optimum (R4/R5/R6 all lost).
// LDS: sAC[64][136] 17408 + sIdx 1536 = 18944.
// ---------------------------------------------------------------------------
__global__ __launch_bounds__(256) void k_mp(const ushort_t* __restrict__ msg_in,
                                            const int* __restrict__ bgraph,
                                            const ushort_t* __restrict__ pWih,
                                            const ushort_t* __restrict__ fbb,
                                            ushort_t* __restrict__ msg_out) {
    __shared__ __align__(16) ushort_t sAC[64][136];   // nei cols 0..127; C overwrites
    __shared__ int sIdx[64][MAX_NB];
    const int t = threadIdx.x;
    const int b0 = blockIdx.x * 64;

    for (int i = t; i < 64 * MAX_NB; i += 256)
        sIdx[i / MAX_NB][i % MAX_NB] = bgraph[(size_t)b0 * MAX_NB + i];
    __syncthreads();

    {   // gather-sum: two merged 12-deep passes, packed fp16 accumulate
        const int bi = t >> 4;
        const int c0 = (t & 15) * 8;
#pragma unroll
        for (int p = 0; p < 4; p += 2) {
            const int iA = p * 16 + bi;
            const int iB = iA + 16;
            uint4 vA[MAX_NB], vB[MAX_NB];
#pragma unroll
            for (int j = 0; j < MAX_NB; ++j)
                vA[j] = *(const uint4*)(msg_in + (size_t)sIdx[iA][j] * H + c0);
#pragma unroll
            for (int j = 0; j < MAX_NB; ++j)
                vB[j] = *(const uint4*)(msg_in + (size_t)sIdx[iB][j] * H + c0);
            uint4 ua = vA[0], ub = vB[0];
#pragma unroll
            for (int j = 1; j < MAX_NB; ++j) addq(ua, vA[j]);
#pragma unroll
            for (int j = 1; j < MAX_NB; ++j) addq(ub, vB[j]);
            *(uint4*)&sAC[iA][c0] = ua;
            *(uint4*)&sAC[iB][c0] = ub;
        }
    }

    const int w    = t >> 6;
    const int lane = t & 63;
    const int col  = lane & 15;
    const int kg   = lane >> 4;
    const int m    = 16 * w + col;

    f16x8 af[KS_IH];
    // fbonds frags direct from global (latency hides under barrier wait)
    af[0] = *(const f16x8*)(fbb + (size_t)(b0 + m) * FBW + kg * 8);
    af[1] = *(const f16x8*)(fbb + (size_t)(b0 + m) * FBW + 32 + kg * 8);
    __syncthreads();
#pragma unroll
    for (int ks = 2; ks < KS_IH; ++ks)
        af[ks] = *(const f16x8*)&sAC[m][(ks - 2) * 32 + kg * 8];

    f32x4 acc[8];
#pragma unroll
    for (int nt = 0; nt < 8; ++nt) acc[nt] = (f32x4){0.f, 0.f, 0.f, 0.f};
#pragma unroll
    for (int ks = 0; ks < KS_IH; ++ks) {
#pragma unroll
        for (int nt = 0; nt < 8; ++nt) {
            const f16x8 b = *(const f16x8*)(pWih + (((size_t)(ks * 8 + nt) * 64 + lane) * 8));
            acc[nt] = __builtin_amdgcn_mfma_f32_16x16x32_f16(af[ks], b, acc[nt], 0, 0, 0);
        }
    }
    // relu + fp16 C into own rows (per-wave slab; af pre-loaded, no barrier)
    const int row0 = kg * 4;
#pragma unroll
    for (int nt = 0; nt < 8; ++nt)
#pragma unroll
        for (int r = 0; r < 4; ++r)
            sAC[16 * w + row0 + r][nt * 16 + col] = f2h(fmaxf(acc[nt][r], 0.f));
    __syncthreads();

    for (int i = t; i < 64 * 16; i += 256) {
        const int row = i >> 4, c0 = (i & 15) * 8;
        *(uint4*)(msg_out + (size_t)(b0 + row) * H + c0) = *(const uint4*)&sAC[row][c0];
    }
}

// ---------------------------------------------------------------------------
// Fused output: out = relu(b_o + [gather(128) | fatoms_f16(64)] @ W_o^T)
// fp16 gather (pk_add); f32 C staged through HALF-width LDS buffer in two
// passes -> coalesced float4 epilogue, full f32 precision, LDS 18944.
// ---------------------------------------------------------------------------
__global__ __launch_bounds__(256) void k_out(const ushort_t* __restrict__ msg,
                                             const int* __restrict__ agraph,
                                             const ushort_t* __restrict__ fab,
                                             const ushort_t* __restrict__ pWo,
                                             const float* __restrict__ b_o,
                                             float* __restrict__ out) {
    __shared__ __align__(16) unsigned char smem[64 * 136 * 2];   // 17408 B union
    ushort_t (*sA)[136] = (ushort_t(*)[136])smem;                // fp16 A tile
    float    (*sCh)[68] = (float(*)[68])smem;                    // f32 C half
    __shared__ int sIdx[64][MAX_NB];
    const int t = threadIdx.x;
    const int a0 = blockIdx.x * 64;

    for (int i = t; i < 64 * MAX_NB; i += 256) {
        const int a = a0 + i / MAX_NB;
        sIdx[i / MAX_NB][i % MAX_NB] = (a < N_ATOMS) ? agraph[(size_t)a * MAX_NB + (i % MAX_NB)] : 0;
    }
    __syncthreads();

    {   // a_nei gather-sum -> cols 0..127, two merged 12-deep passes
        const int bi = t >> 4;
        const int c0 = (t & 15) * 8;
#pragma unroll
        for (int p = 0; p < 4; p += 2) {
            const int iA = p * 16 + bi;
            const int iB = iA + 16;
            uint4 vA[MAX_NB], vB[MAX_NB];
#pragma unroll
            for (int j = 0; j < MAX_NB; ++j)
                vA[j] = *(const uint4*)(msg + (size_t)sIdx[iA][j] * H + c0);
#pragma unroll
            for (int j = 0; j < MAX_NB; ++j)
                vB[j] = *(const uint4*)(msg + (size_t)sIdx[iB][j] * H + c0);
            uint4 ua = vA[0], ub = vB[0];
#pragma unroll
            for (int j = 1; j < MAX_NB; ++j) addq(ua, vA[j]);
#pragma unroll
            for (int j = 1; j < MAX_NB; ++j) addq(ub, vB[j]);
            *(uint4*)&sA[iA][c0] = ua;
            *(uint4*)&sA[iB][c0] = ub;
        }
    }

    const int w    = t >> 6;
    const int lane = t & 63;
    const int col  = lane & 15;
    const int kg   = lane >> 4;
    const int m    = 16 * w + col;
    const int am   = a0 + m;
    const size_t amc = (size_t)((am < N_ATOMS) ? am : 0);   // clamp (unused rows)

    f16x8 af[KS_O];
    af[4] = *(const f16x8*)(fab + amc * FAW + kg * 8);
    af[5] = *(const f16x8*)(fab + amc * FAW + 32 + kg * 8);
    __syncthreads();
#pragma unroll
    for (int ks = 0; ks < 4; ++ks)
        af[ks] = *(const f16x8*)&sA[m][ks * 32 + kg * 8];

    f32x4 acc[8];
#pragma unroll
    for (int nt = 0; nt < 8; ++nt) acc[nt] = (f32x4){0.f, 0.f, 0.f, 0.f};
#pragma unroll
    for (int ks = 0; ks < KS_O; ++ks) {
#pragma unroll
        for (int nt = 0; nt < 8; ++nt) {
            const f16x8 b = *(const f16x8*)(pWo + (((size_t)(ks * 8 + nt) * 64 + lane) * 8));
            acc[nt] = __builtin_amdgcn_mfma_f32_16x16x32_f16(af[ks], b, acc[nt], 0, 0, 0);
        }
    }
    __syncthreads();   // all sA ds_reads done before C-half overwrites (union)

    const int row0 = kg * 4;
    const float4* bo4 = (const float4*)b_o;
#pragma unroll
    for (int half = 0; half < 2; ++half) {
#pragma unroll
        for (int nt = 0; nt < 4; ++nt)
#pragma unroll
            for (int r = 0; r < 4; ++r)
                sCh[16 * w + row0 + r][nt * 16 + col] = acc[half * 4 + nt][r];
        __syncthreads();
        // copy: 64 rows x 64 cols f32 = 4096 = 256 thr x 16 (4x float4)
#pragma unroll
        for (int p = 0; p < 4; ++p) {
            const int i = t + p * 256;
            const int row = i >> 4, c0 = (i & 15) * 4;
            const int a = a0 + row;
            if (a < N_ATOMS) {
                float4 cv = *(const float4*)&sCh[row][c0];
                const float4 bv = bo4[(half * 64 + c0) >> 2];
                cv.x = fmaxf(cv.x + bv.x, 0.f); cv.y = fmaxf(cv.y + bv.y, 0.f);
                cv.z = fmaxf(cv.z + bv.z, 0.f); cv.w = fmaxf(cv.w + bv.w, 0.f);
                *(float4*)(out + (size_t)a * H + half * 64 + c0) = cv;
            }
        }
        if (half == 0) __syncthreads();   // copy reads done before half-1 writes
    }
}

// ---------------------------------------------------------------------------
extern "C" void kernel_launch(void* const* d_in, const int* in_sizes, int n_in,
                              void* d_out, int out_size, void* d_ws, size_t ws_size,
                              hipStream_t stream) {
    const float* fatoms = (const float*)d_in[0];
    const float* fbonds = (const float*)d_in[1];
    const int*   agraph = (const int*)d_in[2];
    const int*   bgraph = (const int*)d_in[3];
    const float* W_i    = (const float*)d_in[4];
    const float* W_h    = (const float*)d_in[5];
    const float* W_o    = (const float*)d_in[6];
    const float* b_o    = (const float*)d_in[7];
    float* out = (float*)d_out;

    const size_t MSG_BYTES = (size_t)N_BONDS * H * sizeof(ushort_t);     // 51.2 MB
    const size_t FBB_BYTES = (size_t)N_BONDS * FBW * sizeof(ushort_t);   // 25.6 MB
    const size_t FAB_BYTES = (size_t)N_ATOMS * FAW * sizeof(ushort_t);   // 12.8 MB
    char* ws = (char*)d_ws;
    ushort_t* m0   = (ushort_t*)(ws);
    ushort_t* m1   = (ushort_t*)(ws + MSG_BYTES);
    ushort_t* fbb  = (ushort_t*)(ws + 2 * MSG_BYTES);
    ushort_t* fab  = (ushort_t*)(ws + 2 * MSG_BYTES + FBB_BYTES);
    char*     wb   = ws + 2 * MSG_BYTES + FBB_BYTES + FAB_BYTES;
    ushort_t* pWi  = (ushort_t*)(wb);              // 16 KB
    ushort_t* pWih = (ushort_t*)(wb + 16 * 1024);  // 48 KB
    ushort_t* pWo  = (ushort_t*)(wb + 64 * 1024);  // 48 KB

    k_pack<<<28, 256, 0, stream>>>(W_i, W_h, W_o, pWi, pWih, pWo);
    k_fab<<<(N_ATOMS + 63) / 64, 256, 0, stream>>>(fatoms, fab);
    k_binput<<<N_BONDS / 64, 256, 0, stream>>>(fbonds, pWi, fbb, m0);

    ushort_t* cur = m0;
    ushort_t* nxt = m1;
    for (int d = 0; d < DEPTH - 1; ++d) {
        k_mp<<<N_BONDS / 64, 256, 0, stream>>>(cur, bgraph, pWih, fbb, nxt);
        ushort_t* tmp = cur; cur = nxt; nxt = tmp;
    }

    k_out<<<(N_ATOMS + 63) / 64, 256, 0, stream>>>(cur, agraph, fab, pWo, b_o, out);
}